// Round 7
// baseline (79.114 us; speedup 1.0000x reference)
//
#include <hip/hip_runtime.h>

#define BATCH 4
#define CH    128
#define HW    128
#define PAD   10
#define PW    148        // x2b rows (128 + 2*10)
#define PWC   160        // x2b row stride in cols (reads up to col 159 stay in-bounds)
#define WIN   21
#define NUV   441
#define NQ    36         // staged B cols per wave (q = dpj + v <= 35)

typedef short s16x8 __attribute__((ext_vector_type(8)));
typedef float f32x4 __attribute__((ext_vector_type(4)));
typedef unsigned short u16x8 __attribute__((ext_vector_type(8)));

static __device__ __forceinline__ unsigned short f32_to_bf16(float f) {
    unsigned int u = __float_as_uint(f);
    u += 0x7FFFu + ((u >> 16) & 1u);       // RNE
    return (unsigned short)(u >> 16);
}

// -------- transpose+convert: x[b][c][i][j] f32 -> channels-last bf16 --------
// One block = ALL 128 channels of one (b, i, 32-wide j tile) -> phase-2 writes
// are full 256 B contiguous rows.
// blocks [0,2048): x1 -> x1b [4][128][128][128]
// blocks [2048,4096): x2 -> x2b [4][148][160][128] at +PAD offsets.
// x2b borders are NEVER written (garbage); mfma epilogue masks those outputs to 0.
__global__ __launch_bounds__(256) void corr_transpose_kernel(
    const float* __restrict__ x1, const float* __restrict__ x2,
    unsigned short* __restrict__ x1b, unsigned short* __restrict__ x2b)
{
    __shared__ float lds[128][33];       // 16.9 KB
    int bidx  = blockIdx.x;
    int which = bidx >= 2048;
    if (which) bidx -= 2048;
    int jt = bidx & 3;
    int i  = (bidx >> 2) & 127;
    int b  = bidx >> 9;
    int j0 = jt * 32;
    int t  = threadIdx.x;

    const float* __restrict__ src = which ? x2 : x1;

    // phase 1: 128 c-rows x 32 j, one float4 per thread per iter (coalesced 128 B/row)
    int cl = t >> 3, jq = t & 7;
    #pragma unroll
    for (int it = 0; it < 4; ++it) {
        int c = it * 32 + cl;
        float4 vv = *(const float4*)&src[(((size_t)b * CH + c) * HW + i) * HW + j0 + jq * 4];
        lds[c][jq * 4 + 0] = vv.x;
        lds[c][jq * 4 + 1] = vv.y;
        lds[c][jq * 4 + 2] = vv.z;
        lds[c][jq * 4 + 3] = vv.w;
    }
    __syncthreads();

    // phase 2: thread -> (j, 8 c's); 16 threads/j-row x 16 B = 256 B dense rows
    int jl = t >> 4, cg = t & 15;
    #pragma unroll
    for (int it = 0; it < 2; ++it) {
        int j = it * 16 + jl;
        u16x8 o;
        #pragma unroll
        for (int k = 0; k < 8; ++k) o[k] = f32_to_bf16(lds[cg * 8 + k][j]);
        if (!which)
            *(u16x8*)&x1b[(((size_t)b * HW + i) * HW + j0 + j) * CH + cg * 8] = o;
        else
            *(u16x8*)&x2b[(((size_t)b * PW + i + PAD) * PWC + (j0 + j + PAD)) * CH + cg * 8] = o;
    }
}

// -------- correlation GEMM, barrier-FREE, 4 blocks/CU --------
// grid: 6144 = 4 b x 32 ti x 8 tj x 6 z (XCD-swizzled). block: 256 thr = 4 waves.
// Pixel tile 4x16 (M=64, mt == dpi). Wave owns region row rr = z*4+w.
// A fragments read DIRECTLY from global (dense 64 B segments; 16 KB tile shared
// by 4 waves -> L1-resident). B row (36 q, contiguous in x2b) staged per-wave in
// LDS via global_load_lds + XOR swizzle. B region is wave-private -> no
// __syncthreads anywhere, just a wave-local vmcnt(0). LDS 36 KB -> 4 blocks/CU.
// Epilogue reuses the wave's own B region as CT scratch (DS pipe in-order).
__global__ __launch_bounds__(256, 4) void corr_mfma_kernel(
    const unsigned short* __restrict__ x1b,
    const unsigned short* __restrict__ x2b,
    float* __restrict__ out)
{
    __shared__ unsigned short ldsB[4 * NQ * 128];   // 36 KB (4 waves x 9 KB)

    int bid  = blockIdx.x;
    int swz  = (bid & 7) * 768 + (bid >> 3);   // XCD-contiguous chunks (6144 % 8 == 0)
    int z    = swz % 6;
    int rest = swz / 6;                        // 0..1023
    int tj   = rest & 7;
    int ti   = (rest >> 3) & 31;
    int b    = rest >> 8;
    int i0 = ti * 4, j0 = tj * 16;

    int t    = threadIdx.x;
    int lane = t & 63;
    int w    = t >> 6;             // wave 0..3
    int l15  = lane & 15;
    int lhi  = lane >> 4;          // 0..3
    int rr   = z * 4 + w;          // owned region row, 0..23

    // ---- stage B row: 36 q x 128 ch contiguous, 9 glds (wave-private) ----
    const unsigned short* rowbase =
        x2b + (((size_t)b * PW + i0 + rr) * PWC + j0) * CH;
    unsigned short* myB = ldsB + w * (NQ * 128);
    #pragma unroll
    for (int g = 0; g < 9; ++g) {
        int ql = lane >> 4;
        int hs = lane & 15;
        int q  = g * 4 + ql;
        int h  = hs ^ (q & 7);     // pre-swizzled global source chunk, linear LDS dest
        const unsigned short* srcp = rowbase + (size_t)q * CH + h * 8;
        __builtin_amdgcn_global_load_lds(
            (const __attribute__((address_space(1))) void*)srcp,
            (__attribute__((address_space(3))) void*)(myB + g * 512),
            16, 0, 0);
    }

    // A fragment base: direct global, dense (lhi x 16 B = 64 B segments)
    const unsigned short* abase =
        x1b + (((size_t)b * HW + i0) * HW + j0 + l15) * CH + lhi * 8;

    // wave-local drain of the 9 glds (no barrier: myB is wave-private)
    asm volatile("s_waitcnt vmcnt(0)" ::: "memory");

    f32x4 acc[3][4];
    #pragma unroll
    for (int ntl = 0; ntl < 3; ++ntl)
        #pragma unroll
        for (int mt = 0; mt < 4; ++mt)
            acc[ntl][mt] = (f32x4)(0.0f);

    const int q0tab[3] = {0, 16, 20};

    #pragma unroll
    for (int kc = 0; kc < 4; ++kc) {
        s16x8 a[4], bb[3];
        #pragma unroll
        for (int mt = 0; mt < 4; ++mt)
            a[mt] = *(const s16x8*)(abase + (size_t)mt * (HW * CH) + kc * 32);
        #pragma unroll
        for (int ntl = 0; ntl < 3; ++ntl) {
            int q    = q0tab[ntl] + l15;
            int slot = (kc * 4 + lhi) ^ (q & 7);
            bb[ntl] = *(const s16x8*)(myB + q * 128 + slot * 8);   // conflict-free b128
        }
        __builtin_amdgcn_s_setprio(1);
        #pragma unroll
        for (int ntl = 0; ntl < 3; ++ntl)
            #pragma unroll
            for (int mt = 0; mt < 4; ++mt)
                acc[ntl][mt] = __builtin_amdgcn_mfma_f32_16x16x32_bf16(a[mt], bb[ntl], acc[ntl][mt], 0, 0, 0);
        __builtin_amdgcn_s_setprio(0);
    }

    // ---- wave-private epilogue: CT scratch overlays this wave's B region ----
    float (*myCT)[20] = (float(*)[20])myB;    // 36 x 20 f32 = 2880 B < 9216 B
    #pragma unroll
    for (int dpi = 0; dpi < 4; ++dpi) {
        int u = rr - dpi;                       // wave-uniform
        if ((unsigned)u < 21u) {
            int r2 = i0 + dpi + u - PAD;        // x2 image row (wave-uniform)
            // dump slice transposed: 4 consecutive dpj (lhi*4+reg) at qc = q0+l15
            #pragma unroll
            for (int ntl = 0; ntl < 3; ++ntl)
                *(f32x4*)&myCT[q0tab[ntl] + l15][lhi * 4] = acc[ntl][dpi];
            // diagonal read (dpj=l15, qc=l15+v), masked coalesced stores
            #pragma unroll
            for (int vb = 0; vb < 6; ++vb) {
                int v = vb * 4 + lhi;
                if (v < 21) {
                    int c2 = j0 + l15 + v - PAD;    // x2 image col (per-lane)
                    float val = myCT[l15 + v][l15];
                    if ((unsigned)r2 >= 128u || (unsigned)c2 >= 128u) val = 0.0f;
                    out[(((size_t)b * NUV + u * WIN + v) * HW + (i0 + dpi)) * HW + j0 + l15] = val;
                }
            }
        }
    }
}

extern "C" void kernel_launch(void* const* d_in, const int* in_sizes, int n_in,
                              void* d_out, int out_size, void* d_ws, size_t ws_size,
                              hipStream_t stream) {
    const float* x1 = (const float*)d_in[0];
    const float* x2 = (const float*)d_in[1];
    float* out = (float*)d_out;

    const size_t X1B_ELEMS = (size_t)BATCH * HW * HW * CH;          // 8,388,608
    const size_t X2B_ELEMS = (size_t)BATCH * PW * PWC * CH;         // 12,124,160
    if (ws_size < (X1B_ELEMS + X2B_ELEMS) * sizeof(unsigned short)) return;

    unsigned short* x1b = (unsigned short*)d_ws;
    unsigned short* x2b = x1b + X1B_ELEMS;

    // No zero-fill: x2b pad region stays garbage; epilogue masks those outputs to 0.
    corr_transpose_kernel<<<4096, 256, 0, stream>>>(x1, x2, x1b, x2b);
    corr_mfma_kernel<<<6144, 256, 0, stream>>>(x1b, x2b, out);
}

// Round 8
// 58.544 us; speedup vs baseline: 1.3513x; 1.3513x over previous
//
#include <hip/hip_runtime.h>

#define BATCH 4
#define CH    128
#define HW    128
#define PAD   10
#define PW    148        // x2b rows (128 + 2*10)
#define PWC   160        // x2b row stride in cols (reads up to col 159 stay in-bounds)
#define WIN   21
#define NUV   441
#define NQ    36         // staged B cols per wave (q = dpj + v <= 35)

typedef short s16x8 __attribute__((ext_vector_type(8)));
typedef float f32x4 __attribute__((ext_vector_type(4)));
typedef unsigned short u16x8 __attribute__((ext_vector_type(8)));

static __device__ __forceinline__ unsigned short f32_to_bf16(float f) {
    unsigned int u = __float_as_uint(f);
    u += 0x7FFFu + ((u >> 16) & 1u);       // RNE
    return (unsigned short)(u >> 16);
}

// -------- transpose+convert x2 ONLY: x2[b][c][i][j] f32 -> channels-last bf16 --------
// 2048 blocks = 4 b x 128 i x 4 j-tiles. x2b [4][148][160][128] at +PAD offsets.
// x2b borders NEVER written (garbage); mfma epilogue masks those outputs to 0.
// (x1 is no longer pre-transposed: corr stages its own A tile from f32 x1.)
__global__ __launch_bounds__(256) void corr_transpose_kernel(
    const float* __restrict__ x2, unsigned short* __restrict__ x2b)
{
    __shared__ float lds[128][33];       // 16.9 KB
    int bidx = blockIdx.x;
    int jt = bidx & 3;
    int i  = (bidx >> 2) & 127;
    int b  = bidx >> 9;
    int j0 = jt * 32;
    int t  = threadIdx.x;

    // phase 1: 128 c-rows x 32 j, one float4 per thread per iter (coalesced 128 B/row)
    int cl = t >> 3, jq = t & 7;
    #pragma unroll
    for (int it = 0; it < 4; ++it) {
        int c = it * 32 + cl;
        float4 vv = *(const float4*)&x2[(((size_t)b * CH + c) * HW + i) * HW + j0 + jq * 4];
        lds[c][jq * 4 + 0] = vv.x;
        lds[c][jq * 4 + 1] = vv.y;
        lds[c][jq * 4 + 2] = vv.z;
        lds[c][jq * 4 + 3] = vv.w;
    }
    __syncthreads();

    // phase 2: thread -> (j, 8 c's); 16 threads/j-row x 16 B = 256 B dense rows
    int jl = t >> 4, cg = t & 15;
    #pragma unroll
    for (int it = 0; it < 2; ++it) {
        int j = it * 16 + jl;
        u16x8 o;
        #pragma unroll
        for (int k = 0; k < 8; ++k) o[k] = f32_to_bf16(lds[cg * 8 + k][j]);
        *(u16x8*)&x2b[(((size_t)b * PW + i + PAD) * PWC + (j0 + j + PAD)) * CH + cg * 8] = o;
    }
}

// -------- correlation GEMM (R5 structure + in-kernel A transpose) --------
// grid: 6144 = 4 b x 32 ti x 8 tj x 6 z (XCD-swizzled). block: 256 thr = 4 waves.
// Pixel tile 4x16 (M=64, mt == dpi). Wave owns region row rr = z*4+w.
// A tile: staged from f32 x1 directly (8 coalesced float4 loads/wave, 16
// c-planes x 64 B segments), cvt to bf16 in-reg, ds_write_b16 into the
// XOR-chunk-swizzled ldsA layout (~2-way bank = free). Fragment reads unchanged.
// B row (36 q contiguous in x2b) staged per-wave via global_load_lds + swizzle.
// One __syncthreads. MFMA q0-tiles {0,16,20}. LDS 52 KB -> 3 blocks/CU.
// Epilogue: wave-private CT restage over own B region, masked coalesced stores.
__global__ __launch_bounds__(256, 3) void corr_mfma_kernel(
    const float* __restrict__ x1,
    const unsigned short* __restrict__ x2b,
    float* __restrict__ out)
{
    __shared__ unsigned short ldsA[64 * 128];       // 16 KB, chunk-swizzled
    __shared__ unsigned short ldsB[4 * NQ * 128];   // 36 KB (4 waves x 9 KB)

    int bid  = blockIdx.x;
    int swz  = (bid & 7) * 768 + (bid >> 3);   // XCD-contiguous chunks (6144 % 8 == 0)
    int z    = swz % 6;
    int rest = swz / 6;                        // 0..1023
    int tj   = rest & 7;
    int ti   = (rest >> 3) & 31;
    int b    = rest >> 8;
    int i0 = ti * 4, j0 = tj * 16;

    int t    = threadIdx.x;
    int lane = t & 63;
    int w    = t >> 6;             // wave 0..3
    int l15  = lane & 15;
    int lhi  = lane >> 4;          // 0..3
    int rr   = z * 4 + w;          // owned region row, 0..23

    // ---- stage B row first (its latency hides under A-cvt work): 9 glds ----
    const unsigned short* rowbase =
        x2b + (((size_t)b * PW + i0 + rr) * PWC + j0) * CH;
    unsigned short* myB = ldsB + w * (NQ * 128);
    #pragma unroll
    for (int g = 0; g < 9; ++g) {
        int ql = lane >> 4;
        int hs = lane & 15;
        int q  = g * 4 + ql;
        int h  = hs ^ (q & 7);     // pre-swizzled global source chunk, linear LDS dest
        const unsigned short* srcp = rowbase + (size_t)q * CH + h * 8;
        __builtin_amdgcn_global_load_lds(
            (const __attribute__((address_space(1))) void*)srcp,
            (__attribute__((address_space(3))) void*)(myB + g * 512),
            16, 0, 0);
    }

    // ---- stage A tile from f32 x1: 8 float4 loads/wave, cvt, swizzled b16 writes ----
    {
        int c16 = lane >> 2;           // 0..15 c within group
        int j4  = lane & 3;            // j quad
        #pragma unroll
        for (int it = 0; it < 8; ++it) {
            int s   = w * 8 + it;      // 0..31
            int dpi = s >> 3;
            int cg  = s & 7;           // c-group of 16
            int c   = cg * 16 + c16;
            float4 vv = *(const float4*)&x1[(((size_t)b * CH + c) * HW + i0 + dpi) * HW + j0 + j4 * 4];
            int h = c >> 3;            // chunk 0..15
            #pragma unroll
            for (int jj = 0; jj < 4; ++jj) {
                int p    = dpi * 16 + j4 * 4 + jj;
                int slot = h ^ (p & 7);
                float fv = (jj == 0) ? vv.x : (jj == 1) ? vv.y : (jj == 2) ? vv.z : vv.w;
                ldsA[p * 128 + slot * 8 + (c16 & 7)] = f32_to_bf16(fv);
            }
        }
    }

    __syncthreads();   // drains glds (vmcnt) + A ds_writes (lgkmcnt); the only barrier

    f32x4 acc[3][4];
    #pragma unroll
    for (int ntl = 0; ntl < 3; ++ntl)
        #pragma unroll
        for (int mt = 0; mt < 4; ++mt)
            acc[ntl][mt] = (f32x4)(0.0f);

    const int q0tab[3] = {0, 16, 20};

    #pragma unroll
    for (int kc = 0; kc < 4; ++kc) {
        s16x8 a[4], bb[3];
        #pragma unroll
        for (int mt = 0; mt < 4; ++mt) {
            int slot = (kc * 4 + lhi) ^ (l15 & 7);
            a[mt] = *(const s16x8*)(ldsA + (mt * 16 + l15) * 128 + slot * 8);
        }
        #pragma unroll
        for (int ntl = 0; ntl < 3; ++ntl) {
            int q    = q0tab[ntl] + l15;
            int slot = (kc * 4 + lhi) ^ (q & 7);
            bb[ntl] = *(const s16x8*)(myB + q * 128 + slot * 8);   // conflict-free b128
        }
        __builtin_amdgcn_s_setprio(1);
        #pragma unroll
        for (int ntl = 0; ntl < 3; ++ntl)
            #pragma unroll
            for (int mt = 0; mt < 4; ++mt)
                acc[ntl][mt] = __builtin_amdgcn_mfma_f32_16x16x32_bf16(a[mt], bb[ntl], acc[ntl][mt], 0, 0, 0);
        __builtin_amdgcn_s_setprio(0);
    }

    // ---- wave-private epilogue: CT scratch overlays this wave's B region ----
    float (*myCT)[20] = (float(*)[20])myB;    // 36 x 20 f32 = 2880 B < 9216 B
    #pragma unroll
    for (int dpi = 0; dpi < 4; ++dpi) {
        int u = rr - dpi;                       // wave-uniform
        if ((unsigned)u < 21u) {
            int r2 = i0 + dpi + u - PAD;        // x2 image row (wave-uniform)
            // dump slice transposed: 4 consecutive dpj (lhi*4+reg) at qc = q0+l15
            #pragma unroll
            for (int ntl = 0; ntl < 3; ++ntl)
                *(f32x4*)&myCT[q0tab[ntl] + l15][lhi * 4] = acc[ntl][dpi];
            // diagonal read (dpj=l15, qc=l15+v), masked coalesced stores
            #pragma unroll
            for (int vb = 0; vb < 6; ++vb) {
                int v = vb * 4 + lhi;
                if (v < 21) {
                    int c2 = j0 + l15 + v - PAD;    // x2 image col (per-lane)
                    float val = myCT[l15 + v][l15];
                    if ((unsigned)r2 >= 128u || (unsigned)c2 >= 128u) val = 0.0f;
                    out[(((size_t)b * NUV + u * WIN + v) * HW + (i0 + dpi)) * HW + j0 + l15] = val;
                }
            }
        }
    }
}

extern "C" void kernel_launch(void* const* d_in, const int* in_sizes, int n_in,
                              void* d_out, int out_size, void* d_ws, size_t ws_size,
                              hipStream_t stream) {
    const float* x1 = (const float*)d_in[0];
    const float* x2 = (const float*)d_in[1];
    float* out = (float*)d_out;

    const size_t X2B_ELEMS = (size_t)BATCH * PW * PWC * CH;         // 12,124,160
    if (ws_size < X2B_ELEMS * sizeof(unsigned short)) return;

    unsigned short* x2b = (unsigned short*)d_ws;

    // No zero-fill: x2b pad region stays garbage; epilogue masks those outputs to 0.
    corr_transpose_kernel<<<2048, 256, 0, stream>>>(x2, x2b);
    corr_mfma_kernel<<<6144, 256, 0, stream>>>(x1, x2b, out);
}

// Round 9
// 53.419 us; speedup vs baseline: 1.4810x; 1.0959x over previous
//
#include <hip/hip_runtime.h>

#define BATCH 4
#define CH    128
#define HW    128
#define PAD   10
#define PW    148        // x2b rows (128 + 2*10)
#define PWC   160        // x2b row stride in cols (reads up to col 159 stay in-bounds)
#define WIN   21
#define NUV   441
#define NQS   40         // staged B cols per wave per half (q<=35 used; 36-39 pad, in-bounds)

typedef short s16x8 __attribute__((ext_vector_type(8)));
typedef float f32x4 __attribute__((ext_vector_type(4)));
typedef unsigned short u16x8 __attribute__((ext_vector_type(8)));

static __device__ __forceinline__ unsigned short f32_to_bf16(float f) {
    unsigned int u = __float_as_uint(f);
    u += 0x7FFFu + ((u >> 16) & 1u);       // RNE
    return (unsigned short)(u >> 16);
}

// -------- transpose+convert: x[b][c][i][j] f32 -> channels-last bf16 (R6 proven) --------
// One block = ALL 128 channels of one (b, i, 32-wide j tile) -> phase-2 writes
// are full 256 B contiguous rows.
// blocks [0,2048): x1 -> x1b [4][128][128][128]
// blocks [2048,4096): x2 -> x2b [4][148][160][128] at +PAD offsets.
// x2b borders NEVER written (garbage); mfma epilogue masks those outputs to 0.
__global__ __launch_bounds__(256) void corr_transpose_kernel(
    const float* __restrict__ x1, const float* __restrict__ x2,
    unsigned short* __restrict__ x1b, unsigned short* __restrict__ x2b)
{
    __shared__ float lds[128][33];       // 16.9 KB
    int bidx  = blockIdx.x;
    int which = bidx >= 2048;
    if (which) bidx -= 2048;
    int jt = bidx & 3;
    int i  = (bidx >> 2) & 127;
    int b  = bidx >> 9;
    int j0 = jt * 32;
    int t  = threadIdx.x;

    const float* __restrict__ src = which ? x2 : x1;

    // phase 1: 128 c-rows x 32 j, one float4 per thread per iter (coalesced 128 B/row)
    int cl = t >> 3, jq = t & 7;
    #pragma unroll
    for (int it = 0; it < 4; ++it) {
        int c = it * 32 + cl;
        float4 vv = *(const float4*)&src[(((size_t)b * CH + c) * HW + i) * HW + j0 + jq * 4];
        lds[c][jq * 4 + 0] = vv.x;
        lds[c][jq * 4 + 1] = vv.y;
        lds[c][jq * 4 + 2] = vv.z;
        lds[c][jq * 4 + 3] = vv.w;
    }
    __syncthreads();

    // phase 2: thread -> (j, 8 c's); 16 threads/j-row x 16 B = 256 B dense rows
    int jl = t >> 4, cg = t & 15;
    #pragma unroll
    for (int it = 0; it < 2; ++it) {
        int j = it * 16 + jl;
        u16x8 o;
        #pragma unroll
        for (int k = 0; k < 8; ++k) o[k] = f32_to_bf16(lds[cg * 8 + k][j]);
        if (!which)
            *(u16x8*)&x1b[(((size_t)b * HW + i) * HW + j0 + j) * CH + cg * 8] = o;
        else
            *(u16x8*)&x2b[(((size_t)b * PW + i + PAD) * PWC + (j0 + j + PAD)) * CH + cg * 8] = o;
    }
}

// -------- correlation GEMM (R6 structure + half-channel B staging, 4 blocks/CU) --------
// grid: 6144 = 4 b x 32 ti x 8 tj x 6 z (XCD-swizzled). block: 256 thr = 4 waves.
// Pixel tile 4x16 (M=64, mt == dpi). Wave owns region row rr = z*4+w.
// A tile (16 KB) staged once via glds + XOR-chunk swizzle; one __syncthreads.
// B row staged WAVE-PRIVATE in two 64-channel halves (5 KB each: 40 q x 128 B,
// 5 glds/half). Half 1 re-staged over the same region after a wave-local
// lgkmcnt(0) drain (DS per-wave in-order; no barrier). LDS = 36 KB -> 4 blk/CU.
// MFMA q0-tiles {0,16,20}. Epilogue: wave-private CT restage, masked stores.
__global__ __launch_bounds__(256, 4) void corr_mfma_kernel(
    const unsigned short* __restrict__ x1b,
    const unsigned short* __restrict__ x2b,
    float* __restrict__ out)
{
    __shared__ unsigned short ldsA[64 * 128];        // 16 KB, chunk-swizzled
    __shared__ unsigned short ldsB[4 * NQS * 64];    // 20 KB (4 waves x 5 KB)

    int bid  = blockIdx.x;
    int swz  = (bid & 7) * 768 + (bid >> 3);   // XCD-contiguous chunks (6144 % 8 == 0)
    int z    = swz % 6;
    int rest = swz / 6;                        // 0..1023
    int tj   = rest & 7;
    int ti   = (rest >> 3) & 31;
    int b    = rest >> 8;
    int i0 = ti * 4, j0 = tj * 16;

    int t    = threadIdx.x;
    int lane = t & 63;
    int w    = t >> 6;             // wave 0..3
    int l15  = lane & 15;
    int lhi  = lane >> 4;          // 0..3
    int rr   = z * 4 + w;          // owned region row, 0..23

    const unsigned short* rowbase =
        x2b + (((size_t)b * PW + i0 + rr) * PWC + j0) * CH;
    unsigned short* myB = ldsB + w * (NQS * 64);

    // lane decomposition for B staging: 8 q per glds (128 B per q-half-row)
    int bq  = lane >> 3;                 // q within 8-group, 0..7
    int bc2 = (lane & 7) ^ bq;           // pre-swizzled source chunk (linear LDS dest)

    // ---- stage A tile: 64 px x 128 ch, 4 glds per wave (1 KB each) ----
    #pragma unroll
    for (int it = 0; it < 4; ++it) {
        int s   = w * 4 + it;          // 0..15
        int dpi = s >> 2;
        int pl  = lane >> 4;
        int hs  = lane & 15;           // dest chunk slot
        int p   = s * 4 + pl;
        int dpj = (s & 3) * 4 + pl;
        int h   = hs ^ (p & 7);        // pre-swizzled global source chunk
        const unsigned short* srcp =
            x1b + (((size_t)b * HW + i0 + dpi) * HW + j0 + dpj) * CH + h * 8;
        __builtin_amdgcn_global_load_lds(
            (const __attribute__((address_space(1))) void*)srcp,
            (__attribute__((address_space(3))) void*)(ldsA + s * 512),
            16, 0, 0);
    }

    // ---- stage B half 0 (ch 0..63): 5 glds, wave-private ----
    #pragma unroll
    for (int g = 0; g < 5; ++g) {
        int q = g * 8 + bq;
        const unsigned short* srcp = rowbase + (size_t)q * CH + bc2 * 8;
        __builtin_amdgcn_global_load_lds(
            (const __attribute__((address_space(1))) void*)srcp,
            (__attribute__((address_space(3))) void*)(myB + g * 512),
            16, 0, 0);
    }

    __syncthreads();   // drains all glds (A is block-shared); the only barrier

    f32x4 acc[3][4];
    #pragma unroll
    for (int ntl = 0; ntl < 3; ++ntl)
        #pragma unroll
        for (int mt = 0; mt < 4; ++mt)
            acc[ntl][mt] = (f32x4)(0.0f);

    const int q0tab[3] = {0, 16, 20};

    #pragma unroll
    for (int ph = 0; ph < 2; ++ph) {
        if (ph == 1) {
            // wave-local: all ph0 fragment ds_reads complete, then overwrite myB
            asm volatile("s_waitcnt lgkmcnt(0)" ::: "memory");
            __builtin_amdgcn_sched_barrier(0);
            #pragma unroll
            for (int g = 0; g < 5; ++g) {
                int q = g * 8 + bq;
                const unsigned short* srcp = rowbase + (size_t)q * CH + 64 + bc2 * 8;
                __builtin_amdgcn_global_load_lds(
                    (const __attribute__((address_space(1))) void*)srcp,
                    (__attribute__((address_space(3))) void*)(myB + g * 512),
                    16, 0, 0);
            }
            asm volatile("s_waitcnt vmcnt(0)" ::: "memory");
            __builtin_amdgcn_sched_barrier(0);
        }
        #pragma unroll
        for (int kc2 = 0; kc2 < 2; ++kc2) {
            int kc = ph * 2 + kc2;
            s16x8 a[4], bb[3];
            #pragma unroll
            for (int mt = 0; mt < 4; ++mt) {
                int slot = (kc * 4 + lhi) ^ (l15 & 7);
                a[mt] = *(const s16x8*)(ldsA + (mt * 16 + l15) * 128 + slot * 8);
            }
            #pragma unroll
            for (int ntl = 0; ntl < 3; ++ntl) {
                int q    = q0tab[ntl] + l15;
                int slot = (kc2 * 4 + lhi) ^ (q & 7);
                bb[ntl] = *(const s16x8*)(myB + q * 64 + slot * 8);   // conflict-free b128
            }
            __builtin_amdgcn_s_setprio(1);
            #pragma unroll
            for (int ntl = 0; ntl < 3; ++ntl)
                #pragma unroll
                for (int mt = 0; mt < 4; ++mt)
                    acc[ntl][mt] = __builtin_amdgcn_mfma_f32_16x16x32_bf16(a[mt], bb[ntl], acc[ntl][mt], 0, 0, 0);
            __builtin_amdgcn_s_setprio(0);
        }
    }

    // ---- wave-private epilogue: CT scratch overlays this wave's B region ----
    float (*myCT)[20] = (float(*)[20])myB;    // 36 x 20 f32 = 2880 B < 5120 B
    #pragma unroll
    for (int dpi = 0; dpi < 4; ++dpi) {
        int u = rr - dpi;                       // wave-uniform
        if ((unsigned)u < 21u) {
            int r2 = i0 + dpi + u - PAD;        // x2 image row (wave-uniform)
            // dump slice transposed: 4 consecutive dpj (lhi*4+reg) at qc = q0+l15
            #pragma unroll
            for (int ntl = 0; ntl < 3; ++ntl)
                *(f32x4*)&myCT[q0tab[ntl] + l15][lhi * 4] = acc[ntl][dpi];
            // diagonal read (dpj=l15, qc=l15+v), masked coalesced stores
            #pragma unroll
            for (int vb = 0; vb < 6; ++vb) {
                int v = vb * 4 + lhi;
                if (v < 21) {
                    int c2 = j0 + l15 + v - PAD;    // x2 image col (per-lane)
                    float val = myCT[l15 + v][l15];
                    if ((unsigned)r2 >= 128u || (unsigned)c2 >= 128u) val = 0.0f;
                    out[(((size_t)b * NUV + u * WIN + v) * HW + (i0 + dpi)) * HW + j0 + l15] = val;
                }
            }
        }
    }
}

extern "C" void kernel_launch(void* const* d_in, const int* in_sizes, int n_in,
                              void* d_out, int out_size, void* d_ws, size_t ws_size,
                              hipStream_t stream) {
    const float* x1 = (const float*)d_in[0];
    const float* x2 = (const float*)d_in[1];
    float* out = (float*)d_out;

    const size_t X1B_ELEMS = (size_t)BATCH * HW * HW * CH;          // 8,388,608
    const size_t X2B_ELEMS = (size_t)BATCH * PW * PWC * CH;         // 12,124,160
    if (ws_size < (X1B_ELEMS + X2B_ELEMS) * sizeof(unsigned short)) return;

    unsigned short* x1b = (unsigned short*)d_ws;
    unsigned short* x2b = x1b + X1B_ELEMS;

    // No zero-fill: x2b pad region stays garbage; epilogue masks those outputs to 0.
    corr_transpose_kernel<<<4096, 256, 0, stream>>>(x1, x2, x1b, x2b);
    corr_mfma_kernel<<<6144, 256, 0, stream>>>(x1b, x2b, out);
}